// Round 7
// baseline (395.789 us; speedup 1.0000x reference)
//
#include <hip/hip_runtime.h>
#include <math.h>

// ---------------------------------------------------------------------------
// RoutingNet round 7: 4 kernels.
//  k_prep : weight transposes ([ic][tap][oc]) + trans_w transpose
//  k_main : 250 blocks x 1024 thr, whole CNN L0..L4 + e per image in LDS
//           (112.6 KB). ic-split+pos-blocked L2/L3 for FMA density.
//  k_rt1  : 100 h-blocks; redundant 3-iter routing (deterministic) + t1 write
//           (no atomics, no zero-init).
//  k_score: 50 blocks x 3 q, shared t1 reads, log_softmax inline.
// ---------------------------------------------------------------------------

#define BN_SCALE rsqrtf(1.0f + 1e-5f)

// ws offsets (floats)
#define OFF_FEATS 0
#define OFF_E     64000
#define OFF_T1    89600
#define OFF_W1T   345600
#define OFF_W2T   350208
#define OFF_W3T   368640
#define OFF_W4T   442368
#define OFF_TWT   737280

// ---- Kernel 1: transposes. 1786*256 = 457216 elements ----
__global__ void k_prep(const float* __restrict__ w1, const float* __restrict__ w2,
                       const float* __restrict__ w3, const float* __restrict__ w4,
                       const float* __restrict__ tw, float* __restrict__ ws) {
  float* w1t = ws + OFF_W1T;
  float* w2t = ws + OFF_W2T;
  float* w3t = ws + OFF_W3T;
  float* w4t = ws + OFF_W4T;
  float* twt = ws + OFF_TWT;
  int i = blockIdx.x * 256 + threadIdx.x;
  if (i < 4608) {                         // w1: OC=32, IC=16
    int oc = i & 31; int r = i >> 5; int tap = r % 9; int ic = r / 9;
    w1t[i] = w1[(oc * 16 + ic) * 9 + tap];
  } else if (i < 23040) {                 // w2: OC=64, IC=32
    int j = i - 4608;
    int oc = j & 63; int r = j >> 6; int tap = r % 9; int ic = r / 9;
    w2t[j] = w2[(oc * 32 + ic) * 9 + tap];
  } else if (i < 96768) {                 // w3: OC=128, IC=64
    int j = i - 23040;
    int oc = j & 127; int r = j >> 7; int tap = r % 9; int ic = r / 9;
    w3t[j] = w3[(oc * 64 + ic) * 9 + tap];
  } else if (i < 391680) {                // w4: OC=256, IC=128
    int j = i - 96768;
    int oc = j & 255; int r = j >> 8; int tap = r % 9; int ic = r / 9;
    w4t[j] = w4[(oc * 128 + ic) * 9 + tap];
  } else {                                // twt[d][c] = tw[c][d]
    int j = i - 391680;
    int d = j >> 8, c = j & 255;
    twt[j] = tw[c * 256 + d];
  }
}

// ---- Kernel 2: whole CNN per image. 250 blocks x 1024 threads ----
// LDS layout (floats):
//   phase L0 : Simg [0,8580) = 65x132 band ; a0pad [8580,28164) = 16x34x36
//   later    : sa1 [0,3968)=32x124(10x12 used), sa2 [4096,7424)=64x52(6x8 used),
//              sa3 [7424,7936)=128x4, sft [7936,8192), RED [8580,24964)=16384
__global__ void __launch_bounds__(1024, 4)
k_main(const float* __restrict__ sup, const float* __restrict__ qry,
       const float* __restrict__ w0, const float* __restrict__ g0, const float* __restrict__ b0,
       const float* __restrict__ g1, const float* __restrict__ b1,
       const float* __restrict__ g2, const float* __restrict__ b2,
       const float* __restrict__ g3, const float* __restrict__ b3,
       const float* __restrict__ g4, const float* __restrict__ b4,
       const float* __restrict__ tb, float* __restrict__ ws,
       float* __restrict__ feats_g, float* __restrict__ e_buf) {
  __shared__ float S[28164];   // 112.6 KB
  const float* w1t = ws + OFF_W1T;
  const float* w2t = ws + OFF_W2T;
  const float* w3t = ws + OFF_W3T;
  const float* w4t = ws + OFF_W4T;
  const float* twt = ws + OFF_TWT;
  const int img = blockIdx.x;
  const int t = threadIdx.x;
  const int lane = t & 63, wid = t >> 6;
  float* a0p = S + 8580;
  float* sa1 = S;
  float* sa2 = S + 4096;
  float* sa3 = S + 7424;
  float* sft = S + 7936;
  float* RED = S + 8580;

  const float* in = (img < 100) ? (sup + (size_t)img * 16384)
                                : (qry + (size_t)(img - 100) * 16384);

  // ---- L0: 1->16ch, 128x128 -s2-> 64x64 -pool-> 32x32, two row-bands ----
  {
    int oc = wid;                       // 16 waves = 16 oc, wave-uniform
    float wv[9];
#pragma unroll
    for (int k = 0; k < 9; k++) wv[k] = w0[oc * 9 + k];
    float sc = g0[oc] * BN_SCALE, bs = b0[oc];
    int pcol = lane & 31, prh = lane >> 5;

    // zero a0pad borders (interior overwritten below)
    for (int i = t; i < 19584; i += 1024) a0p[i] = 0.f;

    for (int pass = 0; pass < 2; pass++) {
      __syncthreads();
      // stage 65 rows: pass0 input rows -1..63, pass1 rows 63..127
      for (int i = t; i < 8580; i += 1024) {
        int r = i / 132, c = i % 132;
        int ir = pass ? (63 + r) : (r - 1);
        int icl = c - 1;
        S[i] = (ir >= 0 && ir < 128 && icl >= 0 && icl < 128) ? in[ir * 128 + icl] : 0.f;
      }
      __syncthreads();
#pragma unroll
      for (int it = 0; it < 8; it++) {
        int prl = it * 2 + prh;          // local pooled row 0..15
        float win[25];
#pragma unroll
        for (int d = 0; d < 5; d++) {
          const float* rp = S + (4 * prl + d) * 132 + 4 * pcol;
          float4 r4 = *(const float4*)rp;
          win[d * 5 + 0] = r4.x; win[d * 5 + 1] = r4.y;
          win[d * 5 + 2] = r4.z; win[d * 5 + 3] = r4.w;
          win[d * 5 + 4] = rp[4];
        }
        float m = -1e30f;
#pragma unroll
        for (int a = 0; a < 2; a++)
#pragma unroll
          for (int b = 0; b < 2; b++) {
            float c = 0.f;
#pragma unroll
            for (int ky = 0; ky < 3; ky++)
#pragma unroll
              for (int kx = 0; kx < 3; kx++)
                c = fmaf(win[(2 * a + ky) * 5 + (2 * b + kx)], wv[ky * 3 + kx], c);
            m = fmaxf(m, fmaf(c, sc, bs));
          }
        int PR = pass * 16 + prl;
        a0p[oc * 1224 + (PR + 1) * 36 + (pcol + 1)] = fmaxf(m, 0.f);
      }
    }
  }
  __syncthreads();
  // zero sa1 + sa2 (overlay dead Simg region)
  for (int i = t; i < 7424; i += 1024) S[i] = 0.f;
  __syncthreads();

  // ---- L1: 16->32ch, 32x32 -s2-> 16x16 -pool-> 8x8 ----
  {
    int ocp = t & 15, pos = t >> 4;
    int py = pos >> 3, px = pos & 7;
    float acc0[4] = {0.f, 0.f, 0.f, 0.f}, acc1[4] = {0.f, 0.f, 0.f, 0.f};
    for (int ic = 0; ic < 16; ic++) {
      float win[25];
      const float* bp = a0p + ic * 1224 + 4 * py * 36 + 4 * px;
#pragma unroll
      for (int d = 0; d < 5; d++) {
        float4 r4 = *(const float4*)(bp + d * 36);
        win[d * 5 + 0] = r4.x; win[d * 5 + 1] = r4.y;
        win[d * 5 + 2] = r4.z; win[d * 5 + 3] = r4.w;
        win[d * 5 + 4] = bp[d * 36 + 4];
      }
      float wA[9], wB[9];
#pragma unroll
      for (int k = 0; k < 9; k++) {
        float2 wv = *(const float2*)(w1t + (ic * 9 + k) * 32 + 2 * ocp);
        wA[k] = wv.x; wB[k] = wv.y;
      }
#pragma unroll
      for (int cy = 0; cy < 2; cy++)
#pragma unroll
        for (int cx = 0; cx < 2; cx++) {
          float c0 = acc0[cy * 2 + cx], c1 = acc1[cy * 2 + cx];
#pragma unroll
          for (int ky = 0; ky < 3; ky++)
#pragma unroll
            for (int kx = 0; kx < 3; kx++) {
              float iv = win[(2 * cy + ky) * 5 + (2 * cx + kx)];
              c0 = fmaf(iv, wA[ky * 3 + kx], c0);
              c1 = fmaf(iv, wB[ky * 3 + kx], c1);
            }
          acc0[cy * 2 + cx] = c0; acc1[cy * 2 + cx] = c1;
        }
    }
#pragma unroll
    for (int j = 0; j < 2; j++) {
      int oc = 2 * ocp + j;
      const float* ac = j ? acc1 : acc0;
      float sc = g1[oc] * BN_SCALE, bsj = b1[oc];
      float m = -1e30f;
#pragma unroll
      for (int p = 0; p < 4; p++) m = fmaxf(m, fmaf(ac[p], sc, bsj));
      sa1[oc * 124 + (py + 1) * 12 + (px + 1)] = fmaxf(m, 0.f);
    }
  }
  __syncthreads();

  // ---- L2: 32->64ch, 8x8 -> pool 4x4. 64oc x 4icg x 4posquad ----
  {
    int oc = t & 63, icg = (t >> 6) & 3, pg = t >> 8;
    int pgy = pg >> 1, pgx = pg & 1;
    float acc[16];
#pragma unroll
    for (int p = 0; p < 16; p++) acc[p] = 0.f;
    for (int ii = 0; ii < 8; ii++) {
      int ic = icg * 8 + ii;
      float win[6][6];
      const float* bp = sa1 + ic * 124 + 4 * pgy * 12 + 4 * pgx;
#pragma unroll
      for (int d = 0; d < 6; d++) {
        float4 u = *(const float4*)(bp + d * 12);
        float2 v = *(const float2*)(bp + d * 12 + 4);
        win[d][0] = u.x; win[d][1] = u.y; win[d][2] = u.z; win[d][3] = u.w;
        win[d][4] = v.x; win[d][5] = v.y;
      }
      const float* wp = w2t + ic * 576 + oc;
      float wr[9];
#pragma unroll
      for (int k = 0; k < 9; k++) wr[k] = wp[k * 64];
#pragma unroll
      for (int u = 0; u < 4; u++)
#pragma unroll
        for (int v = 0; v < 4; v++) {
          float c = acc[u * 4 + v];
#pragma unroll
          for (int ky = 0; ky < 3; ky++)
#pragma unroll
            for (int kx = 0; kx < 3; kx++)
              c = fmaf(win[u + ky][v + kx], wr[ky * 3 + kx], c);
          acc[u * 4 + v] = c;
        }
    }
#pragma unroll
    for (int j = 0; j < 16; j++) RED[j * 1024 + icg * 256 + pg * 64 + oc] = acc[j];
  }
  __syncthreads();
  if (t < 256) {   // L2 reduce + pool + BN + relu
    int oc = t & 63, pg = t >> 6;
    int pgy = pg >> 1, pgx = pg & 1;
    float sc = g2[oc] * BN_SCALE, bsj = b2[oc];
#pragma unroll
    for (int cy = 0; cy < 2; cy++)
#pragma unroll
      for (int cx = 0; cx < 2; cx++) {
        float m = -1e30f;
#pragma unroll
        for (int a = 0; a < 2; a++)
#pragma unroll
          for (int b = 0; b < 2; b++) {
            int j = (2 * cy + a) * 4 + (2 * cx + b);
            float v = RED[j * 1024 + pg * 64 + oc] + RED[j * 1024 + 256 + pg * 64 + oc]
                    + RED[j * 1024 + 512 + pg * 64 + oc] + RED[j * 1024 + 768 + pg * 64 + oc];
            m = fmaxf(m, fmaf(v, sc, bsj));
          }
        sa2[oc * 52 + (1 + 2 * pgy + cy) * 8 + (1 + 2 * pgx + cx)] = fmaxf(m, 0.f);
      }
  }
  __syncthreads();

  // ---- L3: 64->128ch, 4x4 -> pool 2x2. 128oc x 8icg, full window ----
  {
    int oc = t & 127, icg = t >> 7;
    float acc[16];
#pragma unroll
    for (int p = 0; p < 16; p++) acc[p] = 0.f;
    for (int ii = 0; ii < 8; ii++) {
      int ic = icg * 8 + ii;
      float win[6][6];
      const float* bp = sa2 + ic * 52;
#pragma unroll
      for (int d = 0; d < 6; d++) {
        float4 u = *(const float4*)(bp + d * 8);
        float2 v = *(const float2*)(bp + d * 8 + 4);
        win[d][0] = u.x; win[d][1] = u.y; win[d][2] = u.z; win[d][3] = u.w;
        win[d][4] = v.x; win[d][5] = v.y;
      }
      const float* wp = w3t + ic * 1152 + oc;
      float wr[9];
#pragma unroll
      for (int k = 0; k < 9; k++) wr[k] = wp[k * 128];
#pragma unroll
      for (int u = 0; u < 4; u++)
#pragma unroll
        for (int v = 0; v < 4; v++) {
          float c = acc[u * 4 + v];
#pragma unroll
          for (int ky = 0; ky < 3; ky++)
#pragma unroll
            for (int kx = 0; kx < 3; kx++)
              c = fmaf(win[u + ky][v + kx], wr[ky * 3 + kx], c);
          acc[u * 4 + v] = c;
        }
    }
#pragma unroll
    for (int j = 0; j < 16; j++) RED[j * 1024 + icg * 128 + oc] = acc[j];
  }
  __syncthreads();
  if (t < 512) {   // L3 reduce + pool + BN + relu
    int oc = t & 127, pp = t >> 7;
    int py = pp >> 1, px = pp & 1;
    float sc = g3[oc] * BN_SCALE, bsj = b3[oc];
    float m = -1e30f;
#pragma unroll
    for (int a = 0; a < 2; a++)
#pragma unroll
      for (int b = 0; b < 2; b++) {
        int j = (2 * py + a) * 4 + (2 * px + b);
        float v = 0.f;
#pragma unroll
        for (int g = 0; g < 8; g++) v += RED[j * 1024 + g * 128 + oc];
        m = fmaxf(m, fmaf(v, sc, bsj));
      }
    sa3[oc * 4 + pp] = fmaxf(m, 0.f);
  }
  __syncthreads();

  // ---- L4: 128->256ch, 2x2 conv pad1 -> pool 1. 256oc x 4 icq ----
  {
    int oc = t & 255, icq = t >> 8;
    float acc[4] = {0.f, 0.f, 0.f, 0.f};
    for (int ii = 0; ii < 32; ii++) {
      int ic = icq * 32 + ii;
      float4 iv = *(const float4*)(sa3 + ic * 4);
      const float* wp = w4t + ic * 2304 + oc;
      float wr[9];
#pragma unroll
      for (int k = 0; k < 9; k++) wr[k] = wp[k * 256];
#pragma unroll
      for (int py = 0; py < 2; py++)
#pragma unroll
        for (int px = 0; px < 2; px++) {
          float c = acc[py * 2 + px];
          c = fmaf(iv.x, wr[(1 - py) * 3 + (1 - px)], c);
          c = fmaf(iv.y, wr[(1 - py) * 3 + (2 - px)], c);
          c = fmaf(iv.z, wr[(2 - py) * 3 + (1 - px)], c);
          c = fmaf(iv.w, wr[(2 - py) * 3 + (2 - px)], c);
          acc[py * 2 + px] = c;
        }
    }
    if (icq) {
#pragma unroll
      for (int p = 0; p < 4; p++) RED[((icq - 1) * 256 + oc) * 4 + p] = acc[p];
    }
    __syncthreads();
    if (icq == 0) {
      float sc = g4[oc] * BN_SCALE, bsj = b4[oc];
      float m = -1e30f;
#pragma unroll
      for (int p = 0; p < 4; p++) {
        float v = acc[p] + RED[oc * 4 + p] + RED[(256 + oc) * 4 + p] + RED[(512 + oc) * 4 + p];
        m = fmaxf(m, fmaf(v, sc, bsj));
      }
      float r = fmaxf(m, 0.f);
      sft[oc] = r;
      feats_g[(size_t)img * 256 + oc] = r;
    }
  }
  __syncthreads();

  // ---- e[img,c] = dot(feat, tw[c,:]) + tb[c]  (support images only) ----
  if (img < 100) {
    int c = t & 255, dq = t >> 8;
    float acc = 0.f;
#pragma unroll 4
    for (int ii = 0; ii < 64; ii++) {
      int d = dq * 64 + ii;
      acc = fmaf(sft[d], twt[d * 256 + c], acc);
    }
    if (dq) RED[(dq - 1) * 256 + c] = acc;
    __syncthreads();
    if (dq == 0)
      e_buf[img * 256 + c] = acc + RED[c] + RED[256 + c] + RED[512 + c] + tb[c];
  }
}

// ---- Kernel 3: redundant routing + t1[n,h,:] write. 100 h-blocks x 256 ----
__global__ void k_rt1(const float* __restrict__ e, const float* __restrict__ bw,
                      float* __restrict__ t1) {
  __shared__ float pt[3072];    // proto transposed [c][12] (10 used)
  __shared__ float red[4], red2[40];
  const int h = blockIdx.x;
  const int t = threadIdx.x, lane = t & 63, wid = t >> 6;

  for (int n = 0; n < 10; n++) {
    float ek[10];
#pragma unroll
    for (int k = 0; k < 10; k++) ek[k] = e[n * 2560 + k * 256 + t];
    float b[10];
#pragma unroll
    for (int k = 0; k < 10; k++) b[k] = 0.f;
    float cd = 0.f;
    for (int iter = 0; iter < 3; iter++) {
      // softmax of b (uniform across threads)
      float mx = b[0];
#pragma unroll
      for (int k = 1; k < 10; k++) mx = fmaxf(mx, b[k]);
      float sdc[10], sum = 0.f;
#pragma unroll
      for (int k = 0; k < 10; k++) { sdc[k] = expf(b[k] - mx); sum += sdc[k]; }
      float inv = 1.f / sum;
      cd = 0.f;
#pragma unroll
      for (int k = 0; k < 10; k++) cd = fmaf(sdc[k] * inv, ek[k], cd);
      float ss = cd * cd;
#pragma unroll
      for (int off = 32; off > 0; off >>= 1) ss += __shfl_down(ss, off, 64);
      if (lane == 0) red[wid] = ss;
      __syncthreads();
      float tot = red[0] + red[1] + red[2] + red[3];
      cd *= sqrtf(tot) / (tot + 1.f);
      float pr[10];
#pragma unroll
      for (int k = 0; k < 10; k++) pr[k] = cd * ek[k];
#pragma unroll
      for (int off = 32; off > 0; off >>= 1)
#pragma unroll
        for (int k = 0; k < 10; k++) pr[k] += __shfl_down(pr[k], off, 64);
      if (lane == 0)
#pragma unroll
        for (int k = 0; k < 10; k++) red2[k * 4 + wid] = pr[k];
      __syncthreads();
#pragma unroll
      for (int k = 0; k < 10; k++)
        b[k] += red2[k * 4] + red2[k * 4 + 1] + red2[k * 4 + 2] + red2[k * 4 + 3];
      __syncthreads();   // WAR guard before next iter's red/red2 writes
    }
    pt[t * 12 + n] = cd;
  }
  __syncthreads();

  // t1[n,h,e=t] = sum_c pt[c][n] * bw[h,c,e]
  float acc[10];
#pragma unroll
  for (int n = 0; n < 10; n++) acc[n] = 0.f;
  const float* wp = bw + (size_t)h * 65536 + t;
#pragma unroll 2
  for (int c = 0; c < 256; c++) {
    float wv = wp[(size_t)c * 256];
    float4 p0 = *(const float4*)(pt + c * 12);
    float4 p1 = *(const float4*)(pt + c * 12 + 4);
    float2 p2 = *(const float2*)(pt + c * 12 + 8);
    acc[0] = fmaf(p0.x, wv, acc[0]); acc[1] = fmaf(p0.y, wv, acc[1]);
    acc[2] = fmaf(p0.z, wv, acc[2]); acc[3] = fmaf(p0.w, wv, acc[3]);
    acc[4] = fmaf(p1.x, wv, acc[4]); acc[5] = fmaf(p1.y, wv, acc[5]);
    acc[6] = fmaf(p1.z, wv, acc[6]); acc[7] = fmaf(p1.w, wv, acc[7]);
    acc[8] = fmaf(p2.x, wv, acc[8]); acc[9] = fmaf(p2.y, wv, acc[9]);
  }
#pragma unroll
  for (int n = 0; n < 10; n++) t1[((size_t)n * 100 + h) * 256 + t] = acc[n];
}

// ---- Kernel 4: score + log_softmax. 50 blocks x 3 q each ----
__global__ void k_score(const float* __restrict__ t1, const float* __restrict__ qf,
                        const float* __restrict__ sw, const float* __restrict__ sbp,
                        float* __restrict__ out) {
  __shared__ float sred[4][30];
  __shared__ float ssc[30];
  const int q0 = blockIdx.x * 3;
  const int t = threadIdx.x, lane = t & 63, wid = t >> 6;
  float4 qv[3];
#pragma unroll
  for (int j = 0; j < 3; j++) qv[j] = *(const float4*)(qf + (q0 + j) * 256 + lane * 4);
  float accn[3][10];
#pragma unroll
  for (int j = 0; j < 3; j++)
#pragma unroll
    for (int n = 0; n < 10; n++) accn[j][n] = 0.f;
  for (int h = wid * 25; h < wid * 25 + 25; h++) {
    float swh = sw[h];
#pragma unroll
    for (int n = 0; n < 10; n++) {
      float4 tv = *(const float4*)(t1 + ((size_t)n * 100 + h) * 256 + lane * 4);
      float pr[3];
#pragma unroll
      for (int j = 0; j < 3; j++)
        pr[j] = tv.x * qv[j].x + tv.y * qv[j].y + tv.z * qv[j].z + tv.w * qv[j].w;
#pragma unroll
      for (int off = 32; off > 0; off >>= 1)
#pragma unroll
        for (int j = 0; j < 3; j++) pr[j] += __shfl_down(pr[j], off, 64);
      if (lane == 0)
#pragma unroll
        for (int j = 0; j < 3; j++) accn[j][n] = fmaf(fmaxf(pr[j], 0.f), swh, accn[j][n]);
    }
  }
  if (lane == 0)
#pragma unroll
    for (int j = 0; j < 3; j++)
#pragma unroll
      for (int n = 0; n < 10; n++) sred[wid][j * 10 + n] = accn[j][n];
  __syncthreads();
  if (t < 30) ssc[t] = sred[0][t] + sred[1][t] + sred[2][t] + sred[3][t] + sbp[0];
  __syncthreads();
  if (t < 3) {
    float mx = -1e30f;
    for (int n = 0; n < 10; n++) mx = fmaxf(mx, ssc[t * 10 + n]);
    float sum = 0.f;
    for (int n = 0; n < 10; n++) sum += expf(ssc[t * 10 + n] - mx);
    float lse = mx + logf(sum);
    for (int n = 0; n < 10; n++) out[(q0 + t) * 10 + n] = ssc[t * 10 + n] - lse;
  }
}

extern "C" void kernel_launch(void* const* d_in, const int* in_sizes, int n_in,
                              void* d_out, int out_size, void* d_ws, size_t ws_size,
                              hipStream_t stream) {
  const float* support = (const float*)d_in[0];
  const float* query   = (const float*)d_in[1];
  const float* conv_w[5]; const float* bn_g[5]; const float* bn_b[5];
  for (int i = 0; i < 5; i++) {
    conv_w[i] = (const float*)d_in[2 + 3 * i];
    bn_g[i]   = (const float*)d_in[3 + 3 * i];
    bn_b[i]   = (const float*)d_in[4 + 3 * i];
  }
  const float* trans_w = (const float*)d_in[17];
  const float* trans_b = (const float*)d_in[18];
  const float* bil_w   = (const float*)d_in[19];
  const float* score_w = (const float*)d_in[20];
  const float* score_b = (const float*)d_in[21];
  float* out = (float*)d_out;
  float* ws = (float*)d_ws;

  float* feats = ws + OFF_FEATS;
  float* e_buf = ws + OFF_E;
  float* t1    = ws + OFF_T1;

  k_prep<<<1786, 256, 0, stream>>>(conv_w[1], conv_w[2], conv_w[3], conv_w[4],
                                   trans_w, ws);
  k_main<<<250, 1024, 0, stream>>>(support, query,
                                   conv_w[0], bn_g[0], bn_b[0],
                                   bn_g[1], bn_b[1], bn_g[2], bn_b[2],
                                   bn_g[3], bn_b[3], bn_g[4], bn_b[4],
                                   trans_b, ws, feats, e_buf);
  k_rt1<<<100, 256, 0, stream>>>(e_buf, bil_w, t1);
  k_score<<<50, 256, 0, stream>>>(t1, feats + 100 * 256, score_w, score_b, out);
}

// Round 8
// 301.633 us; speedup vs baseline: 1.3122x; 1.3122x over previous
//
#include <hip/hip_runtime.h>
#include <math.h>

// ---------------------------------------------------------------------------
// RoutingNet round 8: kill shuffle-latency tail.
//  k_prep   : weight transposes (unchanged)
//  k_main   : whole CNN per image, 250x1024 (unchanged from R7)
//  k_routing: 10 blocks (R6 version -- fine at this size)
//  k_t1     : 100 h-blocks, no atomics, proto staged transposed in LDS
//  k_score  : per-q block, quad-per-row partial dots in LDS, NO shuffles
// ---------------------------------------------------------------------------

#define BN_SCALE rsqrtf(1.0f + 1e-5f)

// ws offsets (floats)
#define OFF_FEATS 0
#define OFF_E     64000
#define OFF_T1    89600
#define OFF_W1T   345600
#define OFF_W2T   350208
#define OFF_W3T   368640
#define OFF_W4T   442368
#define OFF_TWT   737280
#define OFF_PROTO 802816

// ---- Kernel 1: transposes. 1786*256 = 457216 elements ----
__global__ void k_prep(const float* __restrict__ w1, const float* __restrict__ w2,
                       const float* __restrict__ w3, const float* __restrict__ w4,
                       const float* __restrict__ tw, float* __restrict__ ws) {
  float* w1t = ws + OFF_W1T;
  float* w2t = ws + OFF_W2T;
  float* w3t = ws + OFF_W3T;
  float* w4t = ws + OFF_W4T;
  float* twt = ws + OFF_TWT;
  int i = blockIdx.x * 256 + threadIdx.x;
  if (i < 4608) {
    int oc = i & 31; int r = i >> 5; int tap = r % 9; int ic = r / 9;
    w1t[i] = w1[(oc * 16 + ic) * 9 + tap];
  } else if (i < 23040) {
    int j = i - 4608;
    int oc = j & 63; int r = j >> 6; int tap = r % 9; int ic = r / 9;
    w2t[j] = w2[(oc * 32 + ic) * 9 + tap];
  } else if (i < 96768) {
    int j = i - 23040;
    int oc = j & 127; int r = j >> 7; int tap = r % 9; int ic = r / 9;
    w3t[j] = w3[(oc * 64 + ic) * 9 + tap];
  } else if (i < 391680) {
    int j = i - 96768;
    int oc = j & 255; int r = j >> 8; int tap = r % 9; int ic = r / 9;
    w4t[j] = w4[(oc * 128 + ic) * 9 + tap];
  } else {
    int j = i - 391680;
    int d = j >> 8, c = j & 255;
    twt[j] = tw[c * 256 + d];
  }
}

// ---- Kernel 2: whole CNN per image. 250 blocks x 1024 threads ----
__global__ void __launch_bounds__(1024, 4)
k_main(const float* __restrict__ sup, const float* __restrict__ qry,
       const float* __restrict__ w0, const float* __restrict__ g0, const float* __restrict__ b0,
       const float* __restrict__ g1, const float* __restrict__ b1,
       const float* __restrict__ g2, const float* __restrict__ b2,
       const float* __restrict__ g3, const float* __restrict__ b3,
       const float* __restrict__ g4, const float* __restrict__ b4,
       const float* __restrict__ tb, float* __restrict__ ws,
       float* __restrict__ feats_g, float* __restrict__ e_buf) {
  __shared__ float S[28164];   // 112.6 KB
  const float* w1t = ws + OFF_W1T;
  const float* w2t = ws + OFF_W2T;
  const float* w3t = ws + OFF_W3T;
  const float* w4t = ws + OFF_W4T;
  const float* twt = ws + OFF_TWT;
  const int img = blockIdx.x;
  const int t = threadIdx.x;
  const int lane = t & 63, wid = t >> 6;
  float* a0p = S + 8580;
  float* sa1 = S;
  float* sa2 = S + 4096;
  float* sa3 = S + 7424;
  float* sft = S + 7936;
  float* RED = S + 8580;

  const float* in = (img < 100) ? (sup + (size_t)img * 16384)
                                : (qry + (size_t)(img - 100) * 16384);

  // ---- L0: 1->16ch, 128x128 -s2-> 64x64 -pool-> 32x32, two row-bands ----
  {
    int oc = wid;
    float wv[9];
#pragma unroll
    for (int k = 0; k < 9; k++) wv[k] = w0[oc * 9 + k];
    float sc = g0[oc] * BN_SCALE, bs = b0[oc];
    int pcol = lane & 31, prh = lane >> 5;

    for (int i = t; i < 19584; i += 1024) a0p[i] = 0.f;

    for (int pass = 0; pass < 2; pass++) {
      __syncthreads();
      for (int i = t; i < 8580; i += 1024) {
        int r = i / 132, c = i % 132;
        int ir = pass ? (63 + r) : (r - 1);
        int icl = c - 1;
        S[i] = (ir >= 0 && ir < 128 && icl >= 0 && icl < 128) ? in[ir * 128 + icl] : 0.f;
      }
      __syncthreads();
#pragma unroll
      for (int it = 0; it < 8; it++) {
        int prl = it * 2 + prh;
        float win[25];
#pragma unroll
        for (int d = 0; d < 5; d++) {
          const float* rp = S + (4 * prl + d) * 132 + 4 * pcol;
          float4 r4 = *(const float4*)rp;
          win[d * 5 + 0] = r4.x; win[d * 5 + 1] = r4.y;
          win[d * 5 + 2] = r4.z; win[d * 5 + 3] = r4.w;
          win[d * 5 + 4] = rp[4];
        }
        float m = -1e30f;
#pragma unroll
        for (int a = 0; a < 2; a++)
#pragma unroll
          for (int b = 0; b < 2; b++) {
            float c = 0.f;
#pragma unroll
            for (int ky = 0; ky < 3; ky++)
#pragma unroll
              for (int kx = 0; kx < 3; kx++)
                c = fmaf(win[(2 * a + ky) * 5 + (2 * b + kx)], wv[ky * 3 + kx], c);
            m = fmaxf(m, fmaf(c, sc, bs));
          }
        int PR = pass * 16 + prl;
        a0p[oc * 1224 + (PR + 1) * 36 + (pcol + 1)] = fmaxf(m, 0.f);
      }
    }
  }
  __syncthreads();
  for (int i = t; i < 7424; i += 1024) S[i] = 0.f;
  __syncthreads();

  // ---- L1: 16->32ch ----
  {
    int ocp = t & 15, pos = t >> 4;
    int py = pos >> 3, px = pos & 7;
    float acc0[4] = {0.f, 0.f, 0.f, 0.f}, acc1[4] = {0.f, 0.f, 0.f, 0.f};
    for (int ic = 0; ic < 16; ic++) {
      float win[25];
      const float* bp = a0p + ic * 1224 + 4 * py * 36 + 4 * px;
#pragma unroll
      for (int d = 0; d < 5; d++) {
        float4 r4 = *(const float4*)(bp + d * 36);
        win[d * 5 + 0] = r4.x; win[d * 5 + 1] = r4.y;
        win[d * 5 + 2] = r4.z; win[d * 5 + 3] = r4.w;
        win[d * 5 + 4] = bp[d * 36 + 4];
      }
      float wA[9], wB[9];
#pragma unroll
      for (int k = 0; k < 9; k++) {
        float2 wv = *(const float2*)(w1t + (ic * 9 + k) * 32 + 2 * ocp);
        wA[k] = wv.x; wB[k] = wv.y;
      }
#pragma unroll
      for (int cy = 0; cy < 2; cy++)
#pragma unroll
        for (int cx = 0; cx < 2; cx++) {
          float c0 = acc0[cy * 2 + cx], c1 = acc1[cy * 2 + cx];
#pragma unroll
          for (int ky = 0; ky < 3; ky++)
#pragma unroll
            for (int kx = 0; kx < 3; kx++) {
              float iv = win[(2 * cy + ky) * 5 + (2 * cx + kx)];
              c0 = fmaf(iv, wA[ky * 3 + kx], c0);
              c1 = fmaf(iv, wB[ky * 3 + kx], c1);
            }
          acc0[cy * 2 + cx] = c0; acc1[cy * 2 + cx] = c1;
        }
    }
#pragma unroll
    for (int j = 0; j < 2; j++) {
      int oc = 2 * ocp + j;
      const float* ac = j ? acc1 : acc0;
      float sc = g1[oc] * BN_SCALE, bsj = b1[oc];
      float m = -1e30f;
#pragma unroll
      for (int p = 0; p < 4; p++) m = fmaxf(m, fmaf(ac[p], sc, bsj));
      sa1[oc * 124 + (py + 1) * 12 + (px + 1)] = fmaxf(m, 0.f);
    }
  }
  __syncthreads();

  // ---- L2: 32->64ch ----
  {
    int oc = t & 63, icg = (t >> 6) & 3, pg = t >> 8;
    int pgy = pg >> 1, pgx = pg & 1;
    float acc[16];
#pragma unroll
    for (int p = 0; p < 16; p++) acc[p] = 0.f;
    for (int ii = 0; ii < 8; ii++) {
      int ic = icg * 8 + ii;
      float win[6][6];
      const float* bp = sa1 + ic * 124 + 4 * pgy * 12 + 4 * pgx;
#pragma unroll
      for (int d = 0; d < 6; d++) {
        float4 u = *(const float4*)(bp + d * 12);
        float2 v = *(const float2*)(bp + d * 12 + 4);
        win[d][0] = u.x; win[d][1] = u.y; win[d][2] = u.z; win[d][3] = u.w;
        win[d][4] = v.x; win[d][5] = v.y;
      }
      const float* wp = w2t + ic * 576 + oc;
      float wr[9];
#pragma unroll
      for (int k = 0; k < 9; k++) wr[k] = wp[k * 64];
#pragma unroll
      for (int u = 0; u < 4; u++)
#pragma unroll
        for (int v = 0; v < 4; v++) {
          float c = acc[u * 4 + v];
#pragma unroll
          for (int ky = 0; ky < 3; ky++)
#pragma unroll
            for (int kx = 0; kx < 3; kx++)
              c = fmaf(win[u + ky][v + kx], wr[ky * 3 + kx], c);
          acc[u * 4 + v] = c;
        }
    }
#pragma unroll
    for (int j = 0; j < 16; j++) RED[j * 1024 + icg * 256 + pg * 64 + oc] = acc[j];
  }
  __syncthreads();
  if (t < 256) {
    int oc = t & 63, pg = t >> 6;
    int pgy = pg >> 1, pgx = pg & 1;
    float sc = g2[oc] * BN_SCALE, bsj = b2[oc];
#pragma unroll
    for (int cy = 0; cy < 2; cy++)
#pragma unroll
      for (int cx = 0; cx < 2; cx++) {
        float m = -1e30f;
#pragma unroll
        for (int a = 0; a < 2; a++)
#pragma unroll
          for (int b = 0; b < 2; b++) {
            int j = (2 * cy + a) * 4 + (2 * cx + b);
            float v = RED[j * 1024 + pg * 64 + oc] + RED[j * 1024 + 256 + pg * 64 + oc]
                    + RED[j * 1024 + 512 + pg * 64 + oc] + RED[j * 1024 + 768 + pg * 64 + oc];
            m = fmaxf(m, fmaf(v, sc, bsj));
          }
        sa2[oc * 52 + (1 + 2 * pgy + cy) * 8 + (1 + 2 * pgx + cx)] = fmaxf(m, 0.f);
      }
  }
  __syncthreads();

  // ---- L3: 64->128ch ----
  {
    int oc = t & 127, icg = t >> 7;
    float acc[16];
#pragma unroll
    for (int p = 0; p < 16; p++) acc[p] = 0.f;
    for (int ii = 0; ii < 8; ii++) {
      int ic = icg * 8 + ii;
      float win[6][6];
      const float* bp = sa2 + ic * 52;
#pragma unroll
      for (int d = 0; d < 6; d++) {
        float4 u = *(const float4*)(bp + d * 8);
        float2 v = *(const float2*)(bp + d * 8 + 4);
        win[d][0] = u.x; win[d][1] = u.y; win[d][2] = u.z; win[d][3] = u.w;
        win[d][4] = v.x; win[d][5] = v.y;
      }
      const float* wp = w3t + ic * 1152 + oc;
      float wr[9];
#pragma unroll
      for (int k = 0; k < 9; k++) wr[k] = wp[k * 128];
#pragma unroll
      for (int u = 0; u < 4; u++)
#pragma unroll
        for (int v = 0; v < 4; v++) {
          float c = acc[u * 4 + v];
#pragma unroll
          for (int ky = 0; ky < 3; ky++)
#pragma unroll
            for (int kx = 0; kx < 3; kx++)
              c = fmaf(win[u + ky][v + kx], wr[ky * 3 + kx], c);
          acc[u * 4 + v] = c;
        }
    }
#pragma unroll
    for (int j = 0; j < 16; j++) RED[j * 1024 + icg * 128 + oc] = acc[j];
  }
  __syncthreads();
  if (t < 512) {
    int oc = t & 127, pp = t >> 7;
    int py = pp >> 1, px = pp & 1;
    float sc = g3[oc] * BN_SCALE, bsj = b3[oc];
    float m = -1e30f;
#pragma unroll
    for (int a = 0; a < 2; a++)
#pragma unroll
      for (int b = 0; b < 2; b++) {
        int j = (2 * py + a) * 4 + (2 * px + b);
        float v = 0.f;
#pragma unroll
        for (int g = 0; g < 8; g++) v += RED[j * 1024 + g * 128 + oc];
        m = fmaxf(m, fmaf(v, sc, bsj));
      }
    sa3[oc * 4 + pp] = fmaxf(m, 0.f);
  }
  __syncthreads();

  // ---- L4: 128->256ch ----
  {
    int oc = t & 255, icq = t >> 8;
    float acc[4] = {0.f, 0.f, 0.f, 0.f};
    for (int ii = 0; ii < 32; ii++) {
      int ic = icq * 32 + ii;
      float4 iv = *(const float4*)(sa3 + ic * 4);
      const float* wp = w4t + ic * 2304 + oc;
      float wr[9];
#pragma unroll
      for (int k = 0; k < 9; k++) wr[k] = wp[k * 256];
#pragma unroll
      for (int py = 0; py < 2; py++)
#pragma unroll
        for (int px = 0; px < 2; px++) {
          float c = acc[py * 2 + px];
          c = fmaf(iv.x, wr[(1 - py) * 3 + (1 - px)], c);
          c = fmaf(iv.y, wr[(1 - py) * 3 + (2 - px)], c);
          c = fmaf(iv.z, wr[(2 - py) * 3 + (1 - px)], c);
          c = fmaf(iv.w, wr[(2 - py) * 3 + (2 - px)], c);
          acc[py * 2 + px] = c;
        }
    }
    if (icq) {
#pragma unroll
      for (int p = 0; p < 4; p++) RED[((icq - 1) * 256 + oc) * 4 + p] = acc[p];
    }
    __syncthreads();
    if (icq == 0) {
      float sc = g4[oc] * BN_SCALE, bsj = b4[oc];
      float m = -1e30f;
#pragma unroll
      for (int p = 0; p < 4; p++) {
        float v = acc[p] + RED[oc * 4 + p] + RED[(256 + oc) * 4 + p] + RED[(512 + oc) * 4 + p];
        m = fmaxf(m, fmaf(v, sc, bsj));
      }
      float r = fmaxf(m, 0.f);
      sft[oc] = r;
      feats_g[(size_t)img * 256 + oc] = r;
    }
  }
  __syncthreads();

  // ---- e ----
  if (img < 100) {
    int c = t & 255, dq = t >> 8;
    float acc = 0.f;
#pragma unroll 4
    for (int ii = 0; ii < 64; ii++) {
      int d = dq * 64 + ii;
      acc = fmaf(sft[d], twt[d * 256 + c], acc);
    }
    if (dq) RED[(dq - 1) * 256 + c] = acc;
    __syncthreads();
    if (dq == 0)
      e_buf[img * 256 + c] = acc + RED[c] + RED[256 + c] + RED[512 + c] + tb[c];
  }
}

// ---- Kernel 3: 3-iter routing, 10 blocks (R6 version) ----
__global__ void k_routing(const float* __restrict__ e, float* __restrict__ proto) {
  int n = blockIdx.x;
  __shared__ float sb[10], sdc[10], red[4], red2[40], sfc[1];
  int t = threadIdx.x;
  int lane = t & 63, wid = t >> 6;
  float ek[10];
#pragma unroll
  for (int k = 0; k < 10; k++) ek[k] = e[n * 2560 + k * 256 + t];
  if (t < 10) sb[t] = 0.f;
  __syncthreads();
  float cd = 0.f;
  for (int iter = 0; iter < 3; iter++) {
    if (t == 0) {
      float mx = sb[0];
      for (int k = 1; k < 10; k++) mx = fmaxf(mx, sb[k]);
      float sum = 0.f;
      for (int k = 0; k < 10; k++) { float ex = expf(sb[k] - mx); sdc[k] = ex; sum += ex; }
      float inv = 1.f / sum;
      for (int k = 0; k < 10; k++) sdc[k] *= inv;
    }
    __syncthreads();
    cd = 0.f;
#pragma unroll
    for (int k = 0; k < 10; k++) cd = fmaf(sdc[k], ek[k], cd);
    float ss = cd * cd;
#pragma unroll
    for (int off = 32; off > 0; off >>= 1) ss += __shfl_down(ss, off, 64);
    if (lane == 0) red[wid] = ss;
    __syncthreads();
    if (t == 0) {
      float tot = red[0] + red[1] + red[2] + red[3];
      sfc[0] = sqrtf(tot) / (tot + 1.f);
    }
    __syncthreads();
    cd *= sfc[0];
    float pr[10];
#pragma unroll
    for (int k = 0; k < 10; k++) pr[k] = cd * ek[k];
#pragma unroll
    for (int off = 32; off > 0; off >>= 1)
#pragma unroll
      for (int k = 0; k < 10; k++) pr[k] += __shfl_down(pr[k], off, 64);
    if (lane == 0)
#pragma unroll
      for (int k = 0; k < 10; k++) red2[k * 4 + wid] = pr[k];
    __syncthreads();
    if (t < 10) sb[t] += red2[t * 4] + red2[t * 4 + 1] + red2[t * 4 + 2] + red2[t * 4 + 3];
    __syncthreads();
  }
  proto[n * 256 + t] = cd;
}

// ---- Kernel 4: t1[n,h,:] = sum_c proto[n,c]*bw[h,c,:]. 100 blocks, no atomics ----
__global__ void k_t1(const float* __restrict__ proto, const float* __restrict__ bw,
                     float* __restrict__ t1) {
  __shared__ float pt[3072];    // [c][12], 10 used
  const int h = blockIdx.x;
  const int t = threadIdx.x;
  for (int i = t; i < 2560; i += 256) {
    int n = i >> 8, c = i & 255;
    pt[c * 12 + n] = proto[i];
  }
  __syncthreads();
  float acc[10];
#pragma unroll
  for (int n = 0; n < 10; n++) acc[n] = 0.f;
  const float* wp = bw + (size_t)h * 65536 + t;
#pragma unroll 2
  for (int c = 0; c < 256; c++) {
    float wv = wp[(size_t)c * 256];
    float4 p0 = *(const float4*)(pt + c * 12);
    float4 p1 = *(const float4*)(pt + c * 12 + 4);
    float2 p2 = *(const float2*)(pt + c * 12 + 8);
    acc[0] = fmaf(p0.x, wv, acc[0]); acc[1] = fmaf(p0.y, wv, acc[1]);
    acc[2] = fmaf(p0.z, wv, acc[2]); acc[3] = fmaf(p0.w, wv, acc[3]);
    acc[4] = fmaf(p1.x, wv, acc[4]); acc[5] = fmaf(p1.y, wv, acc[5]);
    acc[6] = fmaf(p1.z, wv, acc[6]); acc[7] = fmaf(p1.w, wv, acc[7]);
    acc[8] = fmaf(p2.x, wv, acc[8]); acc[9] = fmaf(p2.y, wv, acc[9]);
  }
#pragma unroll
  for (int n = 0; n < 10; n++) t1[((size_t)n * 100 + h) * 256 + t] = acc[n];
}

// ---- Kernel 5: score + log_softmax. 150 blocks, one per q. NO shuffles. ----
// Thread-quad owns rows p = quad + 64j; 4 lanes split e (64B-contiguous loads);
// partials to LDS; 10 lanes fold h; thread 0 does log_softmax.
__global__ void k_score(const float* __restrict__ t1, const float* __restrict__ qf,
                        const float* __restrict__ sw, const float* __restrict__ sbp,
                        float* __restrict__ out) {
  __shared__ float sq[256];
  __shared__ float vb[4096];   // [p][s]
  __shared__ float ssum[12];
  const int q = blockIdx.x;
  const int t = threadIdx.x;
  const int s = t & 3, quad = t >> 2;
  sq[t] = qf[q * 256 + t];
  __syncthreads();
  const float4* qr = (const float4*)sq;
#pragma unroll
  for (int j = 0; j < 16; j++) {
    int p = quad + 64 * j;
    if (p < 1000) {
      const float4* row = (const float4*)(t1 + (size_t)p * 256);
      float acc = 0.f;
#pragma unroll
      for (int d = 0; d < 16; d++) {
        float4 a = row[d * 4 + s];
        float4 b = qr[d * 4 + s];
        acc += a.x * b.x + a.y * b.y + a.z * b.z + a.w * b.w;
      }
      vb[p * 4 + s] = acc;
    }
  }
  __syncthreads();
  if (t < 10) {
    float sum = 0.f;
    for (int h = 0; h < 100; h++) {
      int p = t * 100 + h;
      float d = vb[p * 4] + vb[p * 4 + 1] + vb[p * 4 + 2] + vb[p * 4 + 3];
      sum = fmaf(fmaxf(d, 0.f), sw[h], sum);
    }
    ssum[t] = sum + sbp[0];
  }
  __syncthreads();
  if (t == 0) {
    float mx = -1e30f;
    for (int n = 0; n < 10; n++) mx = fmaxf(mx, ssum[n]);
    float sm = 0.f;
    for (int n = 0; n < 10; n++) sm += expf(ssum[n] - mx);
    float lse = mx + logf(sm);
    for (int n = 0; n < 10; n++) out[q * 10 + n] = ssum[n] - lse;
  }
}

extern "C" void kernel_launch(void* const* d_in, const int* in_sizes, int n_in,
                              void* d_out, int out_size, void* d_ws, size_t ws_size,
                              hipStream_t stream) {
  const float* support = (const float*)d_in[0];
  const float* query   = (const float*)d_in[1];
  const float* conv_w[5]; const float* bn_g[5]; const float* bn_b[5];
  for (int i = 0; i < 5; i++) {
    conv_w[i] = (const float*)d_in[2 + 3 * i];
    bn_g[i]   = (const float*)d_in[3 + 3 * i];
    bn_b[i]   = (const float*)d_in[4 + 3 * i];
  }
  const float* trans_w = (const float*)d_in[17];
  const float* trans_b = (const float*)d_in[18];
  const float* bil_w   = (const float*)d_in[19];
  const float* score_w = (const float*)d_in[20];
  const float* score_b = (const float*)d_in[21];
  float* out = (float*)d_out;
  float* ws = (float*)d_ws;

  float* feats = ws + OFF_FEATS;
  float* e_buf = ws + OFF_E;
  float* t1    = ws + OFF_T1;
  float* proto = ws + OFF_PROTO;

  k_prep<<<1786, 256, 0, stream>>>(conv_w[1], conv_w[2], conv_w[3], conv_w[4],
                                   trans_w, ws);
  k_main<<<250, 1024, 0, stream>>>(support, query,
                                   conv_w[0], bn_g[0], bn_b[0],
                                   bn_g[1], bn_b[1], bn_g[2], bn_b[2],
                                   bn_g[3], bn_b[3], bn_g[4], bn_b[4],
                                   trans_b, ws, feats, e_buf);
  k_routing<<<10, 256, 0, stream>>>(e_buf, proto);
  k_t1<<<100, 256, 0, stream>>>(proto, bil_w, t1);
  k_score<<<150, 256, 0, stream>>>(t1, feats + 100 * 256, score_w, score_b, out);
}

// Round 9
// 256.208 us; speedup vs baseline: 1.5448x; 1.1773x over previous
//
#include <hip/hip_runtime.h>
#include <math.h>

// ---------------------------------------------------------------------------
// RoutingNet round 9:
//  k_prep  : weight transposes (unchanged)
//  k_main  : whole CNN per image, 250x1024, + software-pipelined weight loads
//  k_routing: 10 blocks (also zeroes the s accumulator)
//  k_hscore: 100 h-blocks: t1 rows in LDS -> dot vs all q -> atomic s accum
//            (removes t1 global write + 150MB score re-read)
//  k_lsm   : log_softmax, 1 block
// ---------------------------------------------------------------------------

#define BN_SCALE rsqrtf(1.0f + 1e-5f)

// ws offsets (floats)
#define OFF_FEATS 0
#define OFF_E     64000
#define OFF_S     89600
#define OFF_W1T   345600
#define OFF_W2T   350208
#define OFF_W3T   368640
#define OFF_W4T   442368
#define OFF_TWT   737280
#define OFF_PROTO 802816

// ---- Kernel 1: transposes. 1786*256 = 457216 elements ----
__global__ void k_prep(const float* __restrict__ w1, const float* __restrict__ w2,
                       const float* __restrict__ w3, const float* __restrict__ w4,
                       const float* __restrict__ tw, float* __restrict__ ws) {
  float* w1t = ws + OFF_W1T;
  float* w2t = ws + OFF_W2T;
  float* w3t = ws + OFF_W3T;
  float* w4t = ws + OFF_W4T;
  float* twt = ws + OFF_TWT;
  int i = blockIdx.x * 256 + threadIdx.x;
  if (i < 4608) {
    int oc = i & 31; int r = i >> 5; int tap = r % 9; int ic = r / 9;
    w1t[i] = w1[(oc * 16 + ic) * 9 + tap];
  } else if (i < 23040) {
    int j = i - 4608;
    int oc = j & 63; int r = j >> 6; int tap = r % 9; int ic = r / 9;
    w2t[j] = w2[(oc * 32 + ic) * 9 + tap];
  } else if (i < 96768) {
    int j = i - 23040;
    int oc = j & 127; int r = j >> 7; int tap = r % 9; int ic = r / 9;
    w3t[j] = w3[(oc * 64 + ic) * 9 + tap];
  } else if (i < 391680) {
    int j = i - 96768;
    int oc = j & 255; int r = j >> 8; int tap = r % 9; int ic = r / 9;
    w4t[j] = w4[(oc * 128 + ic) * 9 + tap];
  } else {
    int j = i - 391680;
    int d = j >> 8, c = j & 255;
    twt[j] = tw[c * 256 + d];
  }
}

// ---- Kernel 2: whole CNN per image. 250 blocks x 1024 threads ----
__global__ void __launch_bounds__(1024, 4)
k_main(const float* __restrict__ sup, const float* __restrict__ qry,
       const float* __restrict__ w0, const float* __restrict__ g0, const float* __restrict__ b0,
       const float* __restrict__ g1, const float* __restrict__ b1,
       const float* __restrict__ g2, const float* __restrict__ b2,
       const float* __restrict__ g3, const float* __restrict__ b3,
       const float* __restrict__ g4, const float* __restrict__ b4,
       const float* __restrict__ tb, float* __restrict__ ws,
       float* __restrict__ feats_g, float* __restrict__ e_buf) {
  __shared__ float S[28164];   // 112.6 KB
  const float* w1t = ws + OFF_W1T;
  const float* w2t = ws + OFF_W2T;
  const float* w3t = ws + OFF_W3T;
  const float* w4t = ws + OFF_W4T;
  const float* twt = ws + OFF_TWT;
  const int img = blockIdx.x;
  const int t = threadIdx.x;
  const int lane = t & 63, wid = t >> 6;
  float* a0p = S + 8580;
  float* sa1 = S;
  float* sa2 = S + 4096;
  float* sa3 = S + 7424;
  float* sft = S + 7936;
  float* RED = S + 8580;

  const float* in = (img < 100) ? (sup + (size_t)img * 16384)
                                : (qry + (size_t)(img - 100) * 16384);

  // ---- L0: 1->16ch, 128x128 -s2-> 64x64 -pool-> 32x32, two row-bands ----
  {
    int oc = wid;
    float wv[9];
#pragma unroll
    for (int k = 0; k < 9; k++) wv[k] = w0[oc * 9 + k];
    float sc = g0[oc] * BN_SCALE, bs = b0[oc];
    int pcol = lane & 31, prh = lane >> 5;

    for (int i = t; i < 19584; i += 1024) a0p[i] = 0.f;

    for (int pass = 0; pass < 2; pass++) {
      __syncthreads();
      for (int i = t; i < 8580; i += 1024) {
        int r = i / 132, c = i % 132;
        int ir = pass ? (63 + r) : (r - 1);
        int icl = c - 1;
        S[i] = (ir >= 0 && ir < 128 && icl >= 0 && icl < 128) ? in[ir * 128 + icl] : 0.f;
      }
      __syncthreads();
#pragma unroll
      for (int it = 0; it < 8; it++) {
        int prl = it * 2 + prh;
        float win[25];
#pragma unroll
        for (int d = 0; d < 5; d++) {
          const float* rp = S + (4 * prl + d) * 132 + 4 * pcol;
          float4 r4 = *(const float4*)rp;
          win[d * 5 + 0] = r4.x; win[d * 5 + 1] = r4.y;
          win[d * 5 + 2] = r4.z; win[d * 5 + 3] = r4.w;
          win[d * 5 + 4] = rp[4];
        }
        float m = -1e30f;
#pragma unroll
        for (int a = 0; a < 2; a++)
#pragma unroll
          for (int b = 0; b < 2; b++) {
            float c = 0.f;
#pragma unroll
            for (int ky = 0; ky < 3; ky++)
#pragma unroll
              for (int kx = 0; kx < 3; kx++)
                c = fmaf(win[(2 * a + ky) * 5 + (2 * b + kx)], wv[ky * 3 + kx], c);
            m = fmaxf(m, fmaf(c, sc, bs));
          }
        int PR = pass * 16 + prl;
        a0p[oc * 1224 + (PR + 1) * 36 + (pcol + 1)] = fmaxf(m, 0.f);
      }
    }
  }
  __syncthreads();
  for (int i = t; i < 7424; i += 1024) S[i] = 0.f;
  __syncthreads();

  // ---- L1: 16->32ch (weights software-pipelined) ----
  {
    int ocp = t & 15, pos = t >> 4;
    int py = pos >> 3, px = pos & 7;
    float acc0[4] = {0.f, 0.f, 0.f, 0.f}, acc1[4] = {0.f, 0.f, 0.f, 0.f};
    float2 wc[9];
#pragma unroll
    for (int k = 0; k < 9; k++) wc[k] = *(const float2*)(w1t + k * 32 + 2 * ocp);
    for (int ic = 0; ic < 16; ic++) {
      float2 wn[9];
      if (ic < 15) {
#pragma unroll
        for (int k = 0; k < 9; k++)
          wn[k] = *(const float2*)(w1t + ((ic + 1) * 9 + k) * 32 + 2 * ocp);
      }
      float win[25];
      const float* bp = a0p + ic * 1224 + 4 * py * 36 + 4 * px;
#pragma unroll
      for (int d = 0; d < 5; d++) {
        float4 r4 = *(const float4*)(bp + d * 36);
        win[d * 5 + 0] = r4.x; win[d * 5 + 1] = r4.y;
        win[d * 5 + 2] = r4.z; win[d * 5 + 3] = r4.w;
        win[d * 5 + 4] = bp[d * 36 + 4];
      }
#pragma unroll
      for (int cy = 0; cy < 2; cy++)
#pragma unroll
        for (int cx = 0; cx < 2; cx++) {
          float c0 = acc0[cy * 2 + cx], c1 = acc1[cy * 2 + cx];
#pragma unroll
          for (int ky = 0; ky < 3; ky++)
#pragma unroll
            for (int kx = 0; kx < 3; kx++) {
              float iv = win[(2 * cy + ky) * 5 + (2 * cx + kx)];
              c0 = fmaf(iv, wc[ky * 3 + kx].x, c0);
              c1 = fmaf(iv, wc[ky * 3 + kx].y, c1);
            }
          acc0[cy * 2 + cx] = c0; acc1[cy * 2 + cx] = c1;
        }
      if (ic < 15) {
#pragma unroll
        for (int k = 0; k < 9; k++) wc[k] = wn[k];
      }
    }
#pragma unroll
    for (int j = 0; j < 2; j++) {
      int oc = 2 * ocp + j;
      const float* ac = j ? acc1 : acc0;
      float sc = g1[oc] * BN_SCALE, bsj = b1[oc];
      float m = -1e30f;
#pragma unroll
      for (int p = 0; p < 4; p++) m = fmaxf(m, fmaf(ac[p], sc, bsj));
      sa1[oc * 124 + (py + 1) * 12 + (px + 1)] = fmaxf(m, 0.f);
    }
  }
  __syncthreads();

  // ---- L2: 32->64ch (icg-split, pipelined weights) ----
  {
    int oc = t & 63, icg = (t >> 6) & 3, pg = t >> 8;
    int pgy = pg >> 1, pgx = pg & 1;
    float acc[16];
#pragma unroll
    for (int p = 0; p < 16; p++) acc[p] = 0.f;
    float wc[9];
    {
      const float* wp = w2t + (icg * 8) * 576 + oc;
#pragma unroll
      for (int k = 0; k < 9; k++) wc[k] = wp[k * 64];
    }
    for (int ii = 0; ii < 8; ii++) {
      int ic = icg * 8 + ii;
      float wn[9];
      if (ii < 7) {
        const float* wp = w2t + (ic + 1) * 576 + oc;
#pragma unroll
        for (int k = 0; k < 9; k++) wn[k] = wp[k * 64];
      }
      float win[6][6];
      const float* bp = sa1 + ic * 124 + 4 * pgy * 12 + 4 * pgx;
#pragma unroll
      for (int d = 0; d < 6; d++) {
        float4 u = *(const float4*)(bp + d * 12);
        float2 v = *(const float2*)(bp + d * 12 + 4);
        win[d][0] = u.x; win[d][1] = u.y; win[d][2] = u.z; win[d][3] = u.w;
        win[d][4] = v.x; win[d][5] = v.y;
      }
#pragma unroll
      for (int u = 0; u < 4; u++)
#pragma unroll
        for (int v = 0; v < 4; v++) {
          float c = acc[u * 4 + v];
#pragma unroll
          for (int ky = 0; ky < 3; ky++)
#pragma unroll
            for (int kx = 0; kx < 3; kx++)
              c = fmaf(win[u + ky][v + kx], wc[ky * 3 + kx], c);
          acc[u * 4 + v] = c;
        }
      if (ii < 7) {
#pragma unroll
        for (int k = 0; k < 9; k++) wc[k] = wn[k];
      }
    }
#pragma unroll
    for (int j = 0; j < 16; j++) RED[j * 1024 + icg * 256 + pg * 64 + oc] = acc[j];
  }
  __syncthreads();
  if (t < 256) {
    int oc = t & 63, pg = t >> 6;
    int pgy = pg >> 1, pgx = pg & 1;
    float sc = g2[oc] * BN_SCALE, bsj = b2[oc];
#pragma unroll
    for (int cy = 0; cy < 2; cy++)
#pragma unroll
      for (int cx = 0; cx < 2; cx++) {
        float m = -1e30f;
#pragma unroll
        for (int a = 0; a < 2; a++)
#pragma unroll
          for (int b = 0; b < 2; b++) {
            int j = (2 * cy + a) * 4 + (2 * cx + b);
            float v = RED[j * 1024 + pg * 64 + oc] + RED[j * 1024 + 256 + pg * 64 + oc]
                    + RED[j * 1024 + 512 + pg * 64 + oc] + RED[j * 1024 + 768 + pg * 64 + oc];
            m = fmaxf(m, fmaf(v, sc, bsj));
          }
        sa2[oc * 52 + (1 + 2 * pgy + cy) * 8 + (1 + 2 * pgx + cx)] = fmaxf(m, 0.f);
      }
  }
  __syncthreads();

  // ---- L3: 64->128ch (icg-split, pipelined weights) ----
  {
    int oc = t & 127, icg = t >> 7;
    float acc[16];
#pragma unroll
    for (int p = 0; p < 16; p++) acc[p] = 0.f;
    float wc[9];
    {
      const float* wp = w3t + (icg * 8) * 1152 + oc;
#pragma unroll
      for (int k = 0; k < 9; k++) wc[k] = wp[k * 128];
    }
    for (int ii = 0; ii < 8; ii++) {
      int ic = icg * 8 + ii;
      float wn[9];
      if (ii < 7) {
        const float* wp = w3t + (ic + 1) * 1152 + oc;
#pragma unroll
        for (int k = 0; k < 9; k++) wn[k] = wp[k * 128];
      }
      float win[6][6];
      const float* bp = sa2 + ic * 52;
#pragma unroll
      for (int d = 0; d < 6; d++) {
        float4 u = *(const float4*)(bp + d * 8);
        float2 v = *(const float2*)(bp + d * 8 + 4);
        win[d][0] = u.x; win[d][1] = u.y; win[d][2] = u.z; win[d][3] = u.w;
        win[d][4] = v.x; win[d][5] = v.y;
      }
#pragma unroll
      for (int u = 0; u < 4; u++)
#pragma unroll
        for (int v = 0; v < 4; v++) {
          float c = acc[u * 4 + v];
#pragma unroll
          for (int ky = 0; ky < 3; ky++)
#pragma unroll
            for (int kx = 0; kx < 3; kx++)
              c = fmaf(win[u + ky][v + kx], wc[ky * 3 + kx], c);
          acc[u * 4 + v] = c;
        }
      if (ii < 7) {
#pragma unroll
        for (int k = 0; k < 9; k++) wc[k] = wn[k];
      }
    }
#pragma unroll
    for (int j = 0; j < 16; j++) RED[j * 1024 + icg * 128 + oc] = acc[j];
  }
  __syncthreads();
  if (t < 512) {
    int oc = t & 127, pp = t >> 7;
    int py = pp >> 1, px = pp & 1;
    float sc = g3[oc] * BN_SCALE, bsj = b3[oc];
    float m = -1e30f;
#pragma unroll
    for (int a = 0; a < 2; a++)
#pragma unroll
      for (int b = 0; b < 2; b++) {
        int j = (2 * py + a) * 4 + (2 * px + b);
        float v = 0.f;
#pragma unroll
        for (int g = 0; g < 8; g++) v += RED[j * 1024 + g * 128 + oc];
        m = fmaxf(m, fmaf(v, sc, bsj));
      }
    sa3[oc * 4 + pp] = fmaxf(m, 0.f);
  }
  __syncthreads();

  // ---- L4: 128->256ch (icq-split, pipelined weights) ----
  {
    int oc = t & 255, icq = t >> 8;
    float acc[4] = {0.f, 0.f, 0.f, 0.f};
    float wc[9];
    {
      const float* wp = w4t + (icq * 32) * 2304 + oc;
#pragma unroll
      for (int k = 0; k < 9; k++) wc[k] = wp[k * 256];
    }
    for (int ii = 0; ii < 32; ii++) {
      int ic = icq * 32 + ii;
      float wn[9];
      if (ii < 31) {
        const float* wp = w4t + (ic + 1) * 2304 + oc;
#pragma unroll
        for (int k = 0; k < 9; k++) wn[k] = wp[k * 256];
      }
      float4 iv = *(const float4*)(sa3 + ic * 4);
#pragma unroll
      for (int py = 0; py < 2; py++)
#pragma unroll
        for (int px = 0; px < 2; px++) {
          float c = acc[py * 2 + px];
          c = fmaf(iv.x, wc[(1 - py) * 3 + (1 - px)], c);
          c = fmaf(iv.y, wc[(1 - py) * 3 + (2 - px)], c);
          c = fmaf(iv.z, wc[(2 - py) * 3 + (1 - px)], c);
          c = fmaf(iv.w, wc[(2 - py) * 3 + (2 - px)], c);
          acc[py * 2 + px] = c;
        }
      if (ii < 31) {
#pragma unroll
        for (int k = 0; k < 9; k++) wc[k] = wn[k];
      }
    }
    if (icq) {
#pragma unroll
      for (int p = 0; p < 4; p++) RED[((icq - 1) * 256 + oc) * 4 + p] = acc[p];
    }
    __syncthreads();
    if (icq == 0) {
      float sc = g4[oc] * BN_SCALE, bsj = b4[oc];
      float m = -1e30f;
#pragma unroll
      for (int p = 0; p < 4; p++) {
        float v = acc[p] + RED[oc * 4 + p] + RED[(256 + oc) * 4 + p] + RED[(512 + oc) * 4 + p];
        m = fmaxf(m, fmaf(v, sc, bsj));
      }
      float r = fmaxf(m, 0.f);
      sft[oc] = r;
      feats_g[(size_t)img * 256 + oc] = r;
    }
  }
  __syncthreads();

  // ---- e (support images only, pipelined) ----
  if (img < 100) {
    int c = t & 255, dq = t >> 8;
    float acc = 0.f;
    float wv = twt[(dq * 64) * 256 + c];
#pragma unroll 4
    for (int ii = 0; ii < 64; ii++) {
      int d = dq * 64 + ii;
      float wnext = (ii < 63) ? twt[(d + 1) * 256 + c] : 0.f;
      acc = fmaf(sft[d], wv, acc);
      wv = wnext;
    }
    if (dq) RED[(dq - 1) * 256 + c] = acc;
    __syncthreads();
    if (dq == 0)
      e_buf[img * 256 + c] = acc + RED[c] + RED[256 + c] + RED[512 + c] + tb[c];
  }
}

// ---- Kernel 3: 3-iter routing, 10 blocks; also zeroes s accumulator ----
__global__ void k_routing(const float* __restrict__ e, float* __restrict__ proto,
                          float* __restrict__ s) {
  int n = blockIdx.x;
  __shared__ float sb[10], sdc[10], red[4], red2[40], sfc[1];
  int t = threadIdx.x;
  int lane = t & 63, wid = t >> 6;
  if (t < 150) s[n * 150 + t] = 0.f;      // 10 blocks x 150 = all 1500
  float ek[10];
#pragma unroll
  for (int k = 0; k < 10; k++) ek[k] = e[n * 2560 + k * 256 + t];
  if (t < 10) sb[t] = 0.f;
  __syncthreads();
  float cd = 0.f;
  for (int iter = 0; iter < 3; iter++) {
    if (t == 0) {
      float mx = sb[0];
      for (int k = 1; k < 10; k++) mx = fmaxf(mx, sb[k]);
      float sum = 0.f;
      for (int k = 0; k < 10; k++) { float ex = expf(sb[k] - mx); sdc[k] = ex; sum += ex; }
      float inv = 1.f / sum;
      for (int k = 0; k < 10; k++) sdc[k] *= inv;
    }
    __syncthreads();
    cd = 0.f;
#pragma unroll
    for (int k = 0; k < 10; k++) cd = fmaf(sdc[k], ek[k], cd);
    float ss = cd * cd;
#pragma unroll
    for (int off = 32; off > 0; off >>= 1) ss += __shfl_down(ss, off, 64);
    if (lane == 0) red[wid] = ss;
    __syncthreads();
    if (t == 0) {
      float tot = red[0] + red[1] + red[2] + red[3];
      sfc[0] = sqrtf(tot) / (tot + 1.f);
    }
    __syncthreads();
    cd *= sfc[0];
    float pr[10];
#pragma unroll
    for (int k = 0; k < 10; k++) pr[k] = cd * ek[k];
#pragma unroll
    for (int off = 32; off > 0; off >>= 1)
#pragma unroll
      for (int k = 0; k < 10; k++) pr[k] += __shfl_down(pr[k], off, 64);
    if (lane == 0)
#pragma unroll
      for (int k = 0; k < 10; k++) red2[k * 4 + wid] = pr[k];
    __syncthreads();
    if (t < 10) sb[t] += red2[t * 4] + red2[t * 4 + 1] + red2[t * 4 + 2] + red2[t * 4 + 3];
    __syncthreads();
  }
  proto[n * 256 + t] = cd;
}

// ---- Kernel 4: per-h: t1 rows in LDS -> dot vs all q -> atomic s accum ----
// 100 blocks x 256. LDS: pt[3072] + t1L[10*260] + qc[50*260] = 74.7 KB
__global__ void k_hscore(const float* __restrict__ proto, const float* __restrict__ bw,
                         const float* __restrict__ qf, const float* __restrict__ sw,
                         float* __restrict__ s) {
  __shared__ float pt[3072];        // [c][12], 10 used
  __shared__ float t1L[2600];       // [n][260], 256 used
  __shared__ float qc[13000];       // [ql][260], 256 used
  const int h = blockIdx.x;
  const int t = threadIdx.x;
  for (int i = t; i < 2560; i += 256) {
    int n = i >> 8, c = i & 255;
    pt[c * 12 + n] = proto[i];
  }
  __syncthreads();
  // t1 rows for this h
  {
    float acc[10];
#pragma unroll
    for (int n = 0; n < 10; n++) acc[n] = 0.f;
    const float* wp = bw + (size_t)h * 65536 + t;
#pragma unroll 2
    for (int c = 0; c < 256; c++) {
      float wv = wp[(size_t)c * 256];
      float4 p0 = *(const float4*)(pt + c * 12);
      float4 p1 = *(const float4*)(pt + c * 12 + 4);
      float2 p2 = *(const float2*)(pt + c * 12 + 8);
      acc[0] = fmaf(p0.x, wv, acc[0]); acc[1] = fmaf(p0.y, wv, acc[1]);
      acc[2] = fmaf(p0.z, wv, acc[2]); acc[3] = fmaf(p0.w, wv, acc[3]);
      acc[4] = fmaf(p1.x, wv, acc[4]); acc[5] = fmaf(p1.y, wv, acc[5]);
      acc[6] = fmaf(p1.z, wv, acc[6]); acc[7] = fmaf(p1.w, wv, acc[7]);
      acc[8] = fmaf(p2.x, wv, acc[8]); acc[9] = fmaf(p2.y, wv, acc[9]);
    }
#pragma unroll
    for (int n = 0; n < 10; n++) t1L[n * 260 + t] = acc[n];
  }
  float swh = sw[h];
  // 3 chunks of 50 q
  for (int ch = 0; ch < 3; ch++) {
    __syncthreads();   // protect qc (WAR) and t1L readiness on first pass
    int q0 = ch * 50;
    for (int i = t; i < 12800; i += 256) {
      int ql = i >> 8, e = i & 255;
      qc[ql * 260 + e] = qf[(q0 + ql) * 256 + e];
    }
    __syncthreads();
#pragma unroll
    for (int rep = 0; rep < 2; rep++) {
      int p = rep * 256 + t;
      if (p < 500) {
        int ql = p / 10, n = p % 10;
        const float4* tr = (const float4*)(t1L + n * 260);
        const float4* qr = (const float4*)(qc + ql * 260);
        float acc = 0.f;
#pragma unroll 4
        for (int d = 0; d < 64; d++) {
          float4 a = tr[d], b = qr[d];
          acc += a.x * b.x + a.y * b.y + a.z * b.z + a.w * b.w;
        }
        atomicAdd(&s[(q0 + ql) * 10 + n], fmaxf(acc, 0.f) * swh);
      }
    }
  }
}

// ---- Kernel 5: log_softmax. 1 block x 256 ----
__global__ void k_lsm(const float* __restrict__ s, const float* __restrict__ sbp,
                      float* __restrict__ out) {
  int q = threadIdx.x;
  if (q >= 150) return;
  float sb0 = sbp[0];
  float v[10];
  float mx = -1e30f;
#pragma unroll
  for (int n = 0; n < 10; n++) {
    v[n] = s[q * 10 + n] + sb0;
    mx = fmaxf(mx, v[n]);
  }
  float sum = 0.f;
#pragma unroll
  for (int n = 0; n < 10; n++) sum += expf(v[n] - mx);
  float lse = mx + logf(sum);
#pragma unroll
  for (int n = 0; n < 10; n++) out[q * 10 + n] = v[n] - lse;
}

extern "C" void kernel_launch(void* const* d_in, const int* in_sizes, int n_in,
                              void* d_out, int out_size, void* d_ws, size_t ws_size,
                              hipStream_t stream) {
  const float* support = (const float*)d_in[0];
  const float* query   = (const float*)d_in[1];
  const float* conv_w[5]; const float* bn_g[5]; const float* bn_b[5];
  for (int i = 0; i < 5; i++) {
    conv_w[i] = (const float*)d_in[2 + 3 * i];
    bn_g[i]   = (const float*)d_in[3 + 3 * i];
    bn_b[i]   = (const float*)d_in[4 + 3 * i];
  }
  const float* trans_w = (const float*)d_in[17];
  const float* trans_b = (const float*)d_in[18];
  const float* bil_w   = (const float*)d_in[19];
  const float* score_w = (const float*)d_in[20];
  const float* score_b = (const float*)d_in[21];
  float* out = (float*)d_out;
  float* ws = (float*)d_ws;

  float* feats = ws + OFF_FEATS;
  float* e_buf = ws + OFF_E;
  float* s_buf = ws + OFF_S;
  float* proto = ws + OFF_PROTO;

  k_prep<<<1786, 256, 0, stream>>>(conv_w[1], conv_w[2], conv_w[3], conv_w[4],
                                   trans_w, ws);
  k_main<<<250, 1024, 0, stream>>>(support, query,
                                   conv_w[0], bn_g[0], bn_b[0],
                                   bn_g[1], bn_b[1], bn_g[2], bn_b[2],
                                   bn_g[3], bn_b[3], bn_g[4], bn_b[4],
                                   trans_b, ws, feats, e_buf);
  k_routing<<<10, 256, 0, stream>>>(e_buf, proto, s_buf);
  k_hscore<<<100, 256, 0, stream>>>(proto, bil_w, feats + 100 * 256,
                                    score_w, s_buf);
  k_lsm<<<1, 256, 0, stream>>>(s_buf, score_b, out);
}

// Round 10
// 215.884 us; speedup vs baseline: 1.8333x; 1.1868x over previous
//
#include <hip/hip_runtime.h>
#include <math.h>

// ---------------------------------------------------------------------------
// RoutingNet round 10: un-fuse the tail (R9's fused hscore ran at 1 wave/SIMD,
// 80us latency-bound). Grid width > fusion for short streaming phases.
//  k_prep   : transposes + zero t1/s (2793 blocks)
//  k_main   : whole CNN per image, 250x1024 (R9 version, pipelined weights)
//  k_routing: 10 blocks
//  k_t1     : 800 blocks (h x 8 c-chunks), atomicAdd into t1
//  k_score  : 300 blocks (q x 2 h-halves), quad scheme, atomicAdd into s
//  k_lsm    : 1 block
// ---------------------------------------------------------------------------

#define BN_SCALE rsqrtf(1.0f + 1e-5f)

// ws offsets (floats)
#define OFF_FEATS 0
#define OFF_E     64000
#define OFF_S     89600
#define OFF_T1    91136
#define OFF_PROTO 347136
#define OFF_W1T   349696
#define OFF_W2T   354304
#define OFF_W3T   372736
#define OFF_W4T   446464
#define OFF_TWT   741376

// ---- Kernel 1: transposes + zero t1,s. 714716 elems -> 2793 blocks ----
__global__ void k_prep(const float* __restrict__ w1, const float* __restrict__ w2,
                       const float* __restrict__ w3, const float* __restrict__ w4,
                       const float* __restrict__ tw, float* __restrict__ ws) {
  float* w1t = ws + OFF_W1T;
  float* w2t = ws + OFF_W2T;
  float* w3t = ws + OFF_W3T;
  float* w4t = ws + OFF_W4T;
  float* twt = ws + OFF_TWT;
  int i = blockIdx.x * 256 + threadIdx.x;
  if (i < 4608) {
    int oc = i & 31; int r = i >> 5; int tap = r % 9; int ic = r / 9;
    w1t[i] = w1[(oc * 16 + ic) * 9 + tap];
  } else if (i < 23040) {
    int j = i - 4608;
    int oc = j & 63; int r = j >> 6; int tap = r % 9; int ic = r / 9;
    w2t[j] = w2[(oc * 32 + ic) * 9 + tap];
  } else if (i < 96768) {
    int j = i - 23040;
    int oc = j & 127; int r = j >> 7; int tap = r % 9; int ic = r / 9;
    w3t[j] = w3[(oc * 64 + ic) * 9 + tap];
  } else if (i < 391680) {
    int j = i - 96768;
    int oc = j & 255; int r = j >> 8; int tap = r % 9; int ic = r / 9;
    w4t[j] = w4[(oc * 128 + ic) * 9 + tap];
  } else if (i < 457216) {
    int j = i - 391680;
    int d = j >> 8, c = j & 255;
    twt[j] = tw[c * 256 + d];
  } else if (i < 713216) {
    ws[OFF_T1 + (i - 457216)] = 0.f;
  } else if (i < 714716) {
    ws[OFF_S + (i - 713216)] = 0.f;
  }
}

// ---- Kernel 2: whole CNN per image. 250 blocks x 1024 threads ----
__global__ void __launch_bounds__(1024, 4)
k_main(const float* __restrict__ sup, const float* __restrict__ qry,
       const float* __restrict__ w0, const float* __restrict__ g0, const float* __restrict__ b0,
       const float* __restrict__ g1, const float* __restrict__ b1,
       const float* __restrict__ g2, const float* __restrict__ b2,
       const float* __restrict__ g3, const float* __restrict__ b3,
       const float* __restrict__ g4, const float* __restrict__ b4,
       const float* __restrict__ tb, float* __restrict__ ws,
       float* __restrict__ feats_g, float* __restrict__ e_buf) {
  __shared__ float S[28164];   // 112.6 KB
  const float* w1t = ws + OFF_W1T;
  const float* w2t = ws + OFF_W2T;
  const float* w3t = ws + OFF_W3T;
  const float* w4t = ws + OFF_W4T;
  const float* twt = ws + OFF_TWT;
  const int img = blockIdx.x;
  const int t = threadIdx.x;
  const int lane = t & 63, wid = t >> 6;
  float* a0p = S + 8580;
  float* sa1 = S;
  float* sa2 = S + 4096;
  float* sa3 = S + 7424;
  float* sft = S + 7936;
  float* RED = S + 8580;

  const float* in = (img < 100) ? (sup + (size_t)img * 16384)
                                : (qry + (size_t)(img - 100) * 16384);

  // ---- L0 ----
  {
    int oc = wid;
    float wv[9];
#pragma unroll
    for (int k = 0; k < 9; k++) wv[k] = w0[oc * 9 + k];
    float sc = g0[oc] * BN_SCALE, bs = b0[oc];
    int pcol = lane & 31, prh = lane >> 5;

    for (int i = t; i < 19584; i += 1024) a0p[i] = 0.f;

    for (int pass = 0; pass < 2; pass++) {
      __syncthreads();
      for (int i = t; i < 8580; i += 1024) {
        int r = i / 132, c = i % 132;
        int ir = pass ? (63 + r) : (r - 1);
        int icl = c - 1;
        S[i] = (ir >= 0 && ir < 128 && icl >= 0 && icl < 128) ? in[ir * 128 + icl] : 0.f;
      }
      __syncthreads();
#pragma unroll
      for (int it = 0; it < 8; it++) {
        int prl = it * 2 + prh;
        float win[25];
#pragma unroll
        for (int d = 0; d < 5; d++) {
          const float* rp = S + (4 * prl + d) * 132 + 4 * pcol;
          float4 r4 = *(const float4*)rp;
          win[d * 5 + 0] = r4.x; win[d * 5 + 1] = r4.y;
          win[d * 5 + 2] = r4.z; win[d * 5 + 3] = r4.w;
          win[d * 5 + 4] = rp[4];
        }
        float m = -1e30f;
#pragma unroll
        for (int a = 0; a < 2; a++)
#pragma unroll
          for (int b = 0; b < 2; b++) {
            float c = 0.f;
#pragma unroll
            for (int ky = 0; ky < 3; ky++)
#pragma unroll
              for (int kx = 0; kx < 3; kx++)
                c = fmaf(win[(2 * a + ky) * 5 + (2 * b + kx)], wv[ky * 3 + kx], c);
            m = fmaxf(m, fmaf(c, sc, bs));
          }
        int PR = pass * 16 + prl;
        a0p[oc * 1224 + (PR + 1) * 36 + (pcol + 1)] = fmaxf(m, 0.f);
      }
    }
  }
  __syncthreads();
  for (int i = t; i < 7424; i += 1024) S[i] = 0.f;
  __syncthreads();

  // ---- L1 (pipelined weights) ----
  {
    int ocp = t & 15, pos = t >> 4;
    int py = pos >> 3, px = pos & 7;
    float acc0[4] = {0.f, 0.f, 0.f, 0.f}, acc1[4] = {0.f, 0.f, 0.f, 0.f};
    float2 wc[9];
#pragma unroll
    for (int k = 0; k < 9; k++) wc[k] = *(const float2*)(w1t + k * 32 + 2 * ocp);
    for (int ic = 0; ic < 16; ic++) {
      float2 wn[9];
      if (ic < 15) {
#pragma unroll
        for (int k = 0; k < 9; k++)
          wn[k] = *(const float2*)(w1t + ((ic + 1) * 9 + k) * 32 + 2 * ocp);
      }
      float win[25];
      const float* bp = a0p + ic * 1224 + 4 * py * 36 + 4 * px;
#pragma unroll
      for (int d = 0; d < 5; d++) {
        float4 r4 = *(const float4*)(bp + d * 36);
        win[d * 5 + 0] = r4.x; win[d * 5 + 1] = r4.y;
        win[d * 5 + 2] = r4.z; win[d * 5 + 3] = r4.w;
        win[d * 5 + 4] = bp[d * 36 + 4];
      }
#pragma unroll
      for (int cy = 0; cy < 2; cy++)
#pragma unroll
        for (int cx = 0; cx < 2; cx++) {
          float c0 = acc0[cy * 2 + cx], c1 = acc1[cy * 2 + cx];
#pragma unroll
          for (int ky = 0; ky < 3; ky++)
#pragma unroll
            for (int kx = 0; kx < 3; kx++) {
              float iv = win[(2 * cy + ky) * 5 + (2 * cx + kx)];
              c0 = fmaf(iv, wc[ky * 3 + kx].x, c0);
              c1 = fmaf(iv, wc[ky * 3 + kx].y, c1);
            }
          acc0[cy * 2 + cx] = c0; acc1[cy * 2 + cx] = c1;
        }
      if (ic < 15) {
#pragma unroll
        for (int k = 0; k < 9; k++) wc[k] = wn[k];
      }
    }
#pragma unroll
    for (int j = 0; j < 2; j++) {
      int oc = 2 * ocp + j;
      const float* ac = j ? acc1 : acc0;
      float sc = g1[oc] * BN_SCALE, bsj = b1[oc];
      float m = -1e30f;
#pragma unroll
      for (int p = 0; p < 4; p++) m = fmaxf(m, fmaf(ac[p], sc, bsj));
      sa1[oc * 124 + (py + 1) * 12 + (px + 1)] = fmaxf(m, 0.f);
    }
  }
  __syncthreads();

  // ---- L2 (pipelined) ----
  {
    int oc = t & 63, icg = (t >> 6) & 3, pg = t >> 8;
    int pgy = pg >> 1, pgx = pg & 1;
    float acc[16];
#pragma unroll
    for (int p = 0; p < 16; p++) acc[p] = 0.f;
    float wc[9];
    {
      const float* wp = w2t + (icg * 8) * 576 + oc;
#pragma unroll
      for (int k = 0; k < 9; k++) wc[k] = wp[k * 64];
    }
    for (int ii = 0; ii < 8; ii++) {
      int ic = icg * 8 + ii;
      float wn[9];
      if (ii < 7) {
        const float* wp = w2t + (ic + 1) * 576 + oc;
#pragma unroll
        for (int k = 0; k < 9; k++) wn[k] = wp[k * 64];
      }
      float win[6][6];
      const float* bp = sa1 + ic * 124 + 4 * pgy * 12 + 4 * pgx;
#pragma unroll
      for (int d = 0; d < 6; d++) {
        float4 u = *(const float4*)(bp + d * 12);
        float2 v = *(const float2*)(bp + d * 12 + 4);
        win[d][0] = u.x; win[d][1] = u.y; win[d][2] = u.z; win[d][3] = u.w;
        win[d][4] = v.x; win[d][5] = v.y;
      }
#pragma unroll
      for (int u = 0; u < 4; u++)
#pragma unroll
        for (int v = 0; v < 4; v++) {
          float c = acc[u * 4 + v];
#pragma unroll
          for (int ky = 0; ky < 3; ky++)
#pragma unroll
            for (int kx = 0; kx < 3; kx++)
              c = fmaf(win[u + ky][v + kx], wc[ky * 3 + kx], c);
          acc[u * 4 + v] = c;
        }
      if (ii < 7) {
#pragma unroll
        for (int k = 0; k < 9; k++) wc[k] = wn[k];
      }
    }
#pragma unroll
    for (int j = 0; j < 16; j++) RED[j * 1024 + icg * 256 + pg * 64 + oc] = acc[j];
  }
  __syncthreads();
  if (t < 256) {
    int oc = t & 63, pg = t >> 6;
    int pgy = pg >> 1, pgx = pg & 1;
    float sc = g2[oc] * BN_SCALE, bsj = b2[oc];
#pragma unroll
    for (int cy = 0; cy < 2; cy++)
#pragma unroll
      for (int cx = 0; cx < 2; cx++) {
        float m = -1e30f;
#pragma unroll
        for (int a = 0; a < 2; a++)
#pragma unroll
          for (int b = 0; b < 2; b++) {
            int j = (2 * cy + a) * 4 + (2 * cx + b);
            float v = RED[j * 1024 + pg * 64 + oc] + RED[j * 1024 + 256 + pg * 64 + oc]
                    + RED[j * 1024 + 512 + pg * 64 + oc] + RED[j * 1024 + 768 + pg * 64 + oc];
            m = fmaxf(m, fmaf(v, sc, bsj));
          }
        sa2[oc * 52 + (1 + 2 * pgy + cy) * 8 + (1 + 2 * pgx + cx)] = fmaxf(m, 0.f);
      }
  }
  __syncthreads();

  // ---- L3 (pipelined) ----
  {
    int oc = t & 127, icg = t >> 7;
    float acc[16];
#pragma unroll
    for (int p = 0; p < 16; p++) acc[p] = 0.f;
    float wc[9];
    {
      const float* wp = w3t + (icg * 8) * 1152 + oc;
#pragma unroll
      for (int k = 0; k < 9; k++) wc[k] = wp[k * 128];
    }
    for (int ii = 0; ii < 8; ii++) {
      int ic = icg * 8 + ii;
      float wn[9];
      if (ii < 7) {
        const float* wp = w3t + (ic + 1) * 1152 + oc;
#pragma unroll
        for (int k = 0; k < 9; k++) wn[k] = wp[k * 128];
      }
      float win[6][6];
      const float* bp = sa2 + ic * 52;
#pragma unroll
      for (int d = 0; d < 6; d++) {
        float4 u = *(const float4*)(bp + d * 8);
        float2 v = *(const float2*)(bp + d * 8 + 4);
        win[d][0] = u.x; win[d][1] = u.y; win[d][2] = u.z; win[d][3] = u.w;
        win[d][4] = v.x; win[d][5] = v.y;
      }
#pragma unroll
      for (int u = 0; u < 4; u++)
#pragma unroll
        for (int v = 0; v < 4; v++) {
          float c = acc[u * 4 + v];
#pragma unroll
          for (int ky = 0; ky < 3; ky++)
#pragma unroll
            for (int kx = 0; kx < 3; kx++)
              c = fmaf(win[u + ky][v + kx], wc[ky * 3 + kx], c);
          acc[u * 4 + v] = c;
        }
      if (ii < 7) {
#pragma unroll
        for (int k = 0; k < 9; k++) wc[k] = wn[k];
      }
    }
#pragma unroll
    for (int j = 0; j < 16; j++) RED[j * 1024 + icg * 128 + oc] = acc[j];
  }
  __syncthreads();
  if (t < 512) {
    int oc = t & 127, pp = t >> 7;
    int py = pp >> 1, px = pp & 1;
    float sc = g3[oc] * BN_SCALE, bsj = b3[oc];
    float m = -1e30f;
#pragma unroll
    for (int a = 0; a < 2; a++)
#pragma unroll
      for (int b = 0; b < 2; b++) {
        int j = (2 * py + a) * 4 + (2 * px + b);
        float v = 0.f;
#pragma unroll
        for (int g = 0; g < 8; g++) v += RED[j * 1024 + g * 128 + oc];
        m = fmaxf(m, fmaf(v, sc, bsj));
      }
    sa3[oc * 4 + pp] = fmaxf(m, 0.f);
  }
  __syncthreads();

  // ---- L4 (pipelined) ----
  {
    int oc = t & 255, icq = t >> 8;
    float acc[4] = {0.f, 0.f, 0.f, 0.f};
    float wc[9];
    {
      const float* wp = w4t + (icq * 32) * 2304 + oc;
#pragma unroll
      for (int k = 0; k < 9; k++) wc[k] = wp[k * 256];
    }
    for (int ii = 0; ii < 32; ii++) {
      int ic = icq * 32 + ii;
      float wn[9];
      if (ii < 31) {
        const float* wp = w4t + (ic + 1) * 2304 + oc;
#pragma unroll
        for (int k = 0; k < 9; k++) wn[k] = wp[k * 256];
      }
      float4 iv = *(const float4*)(sa3 + ic * 4);
#pragma unroll
      for (int py = 0; py < 2; py++)
#pragma unroll
        for (int px = 0; px < 2; px++) {
          float c = acc[py * 2 + px];
          c = fmaf(iv.x, wc[(1 - py) * 3 + (1 - px)], c);
          c = fmaf(iv.y, wc[(1 - py) * 3 + (2 - px)], c);
          c = fmaf(iv.z, wc[(2 - py) * 3 + (1 - px)], c);
          c = fmaf(iv.w, wc[(2 - py) * 3 + (2 - px)], c);
          acc[py * 2 + px] = c;
        }
      if (ii < 31) {
#pragma unroll
        for (int k = 0; k < 9; k++) wc[k] = wn[k];
      }
    }
    if (icq) {
#pragma unroll
      for (int p = 0; p < 4; p++) RED[((icq - 1) * 256 + oc) * 4 + p] = acc[p];
    }
    __syncthreads();
    if (icq == 0) {
      float sc = g4[oc] * BN_SCALE, bsj = b4[oc];
      float m = -1e30f;
#pragma unroll
      for (int p = 0; p < 4; p++) {
        float v = acc[p] + RED[oc * 4 + p] + RED[(256 + oc) * 4 + p] + RED[(512 + oc) * 4 + p];
        m = fmaxf(m, fmaf(v, sc, bsj));
      }
      float r = fmaxf(m, 0.f);
      sft[oc] = r;
      feats_g[(size_t)img * 256 + oc] = r;
    }
  }
  __syncthreads();

  // ---- e ----
  if (img < 100) {
    int c = t & 255, dq = t >> 8;
    float acc = 0.f;
    float wv = twt[(dq * 64) * 256 + c];
#pragma unroll 4
    for (int ii = 0; ii < 64; ii++) {
      int d = dq * 64 + ii;
      float wnext = (ii < 63) ? twt[(d + 1) * 256 + c] : 0.f;
      acc = fmaf(sft[d], wv, acc);
      wv = wnext;
    }
    if (dq) RED[(dq - 1) * 256 + c] = acc;
    __syncthreads();
    if (dq == 0)
      e_buf[img * 256 + c] = acc + RED[c] + RED[256 + c] + RED[512 + c] + tb[c];
  }
}

// ---- Kernel 3: 3-iter routing, 10 blocks ----
__global__ void k_routing(const float* __restrict__ e, float* __restrict__ proto) {
  int n = blockIdx.x;
  __shared__ float sb[10], sdc[10], red[4], red2[40], sfc[1];
  int t = threadIdx.x;
  int lane = t & 63, wid = t >> 6;
  float ek[10];
#pragma unroll
  for (int k = 0; k < 10; k++) ek[k] = e[n * 2560 + k * 256 + t];
  if (t < 10) sb[t] = 0.f;
  __syncthreads();
  float cd = 0.f;
  for (int iter = 0; iter < 3; iter++) {
    if (t == 0) {
      float mx = sb[0];
      for (int k = 1; k < 10; k++) mx = fmaxf(mx, sb[k]);
      float sum = 0.f;
      for (int k = 0; k < 10; k++) { float ex = expf(sb[k] - mx); sdc[k] = ex; sum += ex; }
      float inv = 1.f / sum;
      for (int k = 0; k < 10; k++) sdc[k] *= inv;
    }
    __syncthreads();
    cd = 0.f;
#pragma unroll
    for (int k = 0; k < 10; k++) cd = fmaf(sdc[k], ek[k], cd);
    float ss = cd * cd;
#pragma unroll
    for (int off = 32; off > 0; off >>= 1) ss += __shfl_down(ss, off, 64);
    if (lane == 0) red[wid] = ss;
    __syncthreads();
    if (t == 0) {
      float tot = red[0] + red[1] + red[2] + red[3];
      sfc[0] = sqrtf(tot) / (tot + 1.f);
    }
    __syncthreads();
    cd *= sfc[0];
    float pr[10];
#pragma unroll
    for (int k = 0; k < 10; k++) pr[k] = cd * ek[k];
#pragma unroll
    for (int off = 32; off > 0; off >>= 1)
#pragma unroll
      for (int k = 0; k < 10; k++) pr[k] += __shfl_down(pr[k], off, 64);
    if (lane == 0)
#pragma unroll
      for (int k = 0; k < 10; k++) red2[k * 4 + wid] = pr[k];
    __syncthreads();
    if (t < 10) sb[t] += red2[t * 4] + red2[t * 4 + 1] + red2[t * 4 + 2] + red2[t * 4 + 3];
    __syncthreads();
  }
  proto[n * 256 + t] = cd;
}

// ---- Kernel 4: t1 accumulation. 800 blocks (h x 8 c-chunks of 32) ----
__global__ void k_t1(const float* __restrict__ proto, const float* __restrict__ bw,
                     float* __restrict__ t1) {
  __shared__ float pt[384];   // [cl][12], 10 used
  const int b = blockIdx.x;
  const int h = b >> 3, c0 = (b & 7) * 32;
  const int t = threadIdx.x;
  for (int i = t; i < 320; i += 256) {
    int n = i >> 5, cl = i & 31;
    pt[cl * 12 + n] = proto[n * 256 + c0 + cl];
  }
  __syncthreads();
  float acc[10];
#pragma unroll
  for (int n = 0; n < 10; n++) acc[n] = 0.f;
  const float* wp = bw + (size_t)h * 65536 + (size_t)c0 * 256 + t;
#pragma unroll 4
  for (int cl = 0; cl < 32; cl++) {
    float wv = wp[(size_t)cl * 256];
    float4 p0 = *(const float4*)(pt + cl * 12);
    float4 p1 = *(const float4*)(pt + cl * 12 + 4);
    float2 p2 = *(const float2*)(pt + cl * 12 + 8);
    acc[0] = fmaf(p0.x, wv, acc[0]); acc[1] = fmaf(p0.y, wv, acc[1]);
    acc[2] = fmaf(p0.z, wv, acc[2]); acc[3] = fmaf(p0.w, wv, acc[3]);
    acc[4] = fmaf(p1.x, wv, acc[4]); acc[5] = fmaf(p1.y, wv, acc[5]);
    acc[6] = fmaf(p1.z, wv, acc[6]); acc[7] = fmaf(p1.w, wv, acc[7]);
    acc[8] = fmaf(p2.x, wv, acc[8]); acc[9] = fmaf(p2.y, wv, acc[9]);
  }
#pragma unroll
  for (int n = 0; n < 10; n++)
    atomicAdd(&t1[((size_t)n * 100 + h) * 256 + t], acc[n]);
}

// ---- Kernel 5: score partials. 300 blocks (q x 2 h-halves), no shuffles ----
__global__ void k_score(const float* __restrict__ t1, const float* __restrict__ qf,
                        const float* __restrict__ sw, float* __restrict__ s) {
  __shared__ float sq[256];
  __shared__ float vb[2000];   // [lr][4]
  const int q = blockIdx.x >> 1, hh = blockIdx.x & 1;
  const int t = threadIdx.x;
  const int sl = t & 3, quad = t >> 2;
  sq[t] = qf[q * 256 + t];
  __syncthreads();
  const float4* qr = (const float4*)sq;
#pragma unroll
  for (int j = 0; j < 8; j++) {
    int lr = quad + 64 * j;          // local row 0..511
    if (lr < 500) {
      int n = lr / 50, hl = lr % 50;
      const float4* row = (const float4*)(t1 + ((size_t)(n * 100 + hh * 50 + hl)) * 256);
      float acc = 0.f;
#pragma unroll
      for (int d = 0; d < 16; d++) {
        float4 a = row[d * 4 + sl];
        float4 b = qr[d * 4 + sl];
        acc += a.x * b.x + a.y * b.y + a.z * b.z + a.w * b.w;
      }
      vb[lr * 4 + sl] = acc;
    }
  }
  __syncthreads();
  if (t < 10) {
    float sum = 0.f;
    for (int hl = 0; hl < 50; hl++) {
      int lr = t * 50 + hl;
      float d = vb[lr * 4] + vb[lr * 4 + 1] + vb[lr * 4 + 2] + vb[lr * 4 + 3];
      sum = fmaf(fmaxf(d, 0.f), sw[hh * 50 + hl], sum);
    }
    atomicAdd(&s[q * 10 + t], sum);
  }
}

// ---- Kernel 6: log_softmax. 1 block x 256 ----
__global__ void k_lsm(const float* __restrict__ s, const float* __restrict__ sbp,
                      float* __restrict__ out) {
  int q = threadIdx.x;
  if (q >= 150) return;
  float sb0 = sbp[0];
  float v[10];
  float mx = -1e30f;
#pragma unroll
  for (int n = 0; n < 10; n++) {
    v[n] = s[q * 10 + n] + sb0;
    mx = fmaxf(mx, v[n]);
  }
  float sum = 0.f;
#pragma unroll
  for (int n = 0; n < 10; n++) sum += expf(v[n] - mx);
  float lse = mx + logf(sum);
#pragma unroll
  for (int n = 0; n < 10; n++) out[q * 10 + n] = v[n] - lse;
}

extern "C" void kernel_launch(void* const* d_in, const int* in_sizes, int n_in,
                              void* d_out, int out_size, void* d_ws, size_t ws_size,
                              hipStream_t stream) {
  const float* support = (const float*)d_in[0];
  const float* query   = (const float*)d_in[1];
  const float* conv_w[5]; const float* bn_g[5]; const float* bn_b[5];
  for (int i = 0; i < 5; i++) {
    conv_w[i] = (const float*)d_in[2 + 3 * i];
    bn_g[i]   = (const float*)d_in[3 + 3 * i];
    bn_b[i]   = (const float*)d_in[4 + 3 * i];
  }
  const float* trans_w = (const float*)d_in[17];
  const float* trans_b = (const float*)d_in[18];
  const float* bil_w   = (const float*)d_in[19];
  const float* score_w = (const float*)d_in[20];
  const float* score_b = (const float*)d_in[21];
  float* out = (float*)d_out;
  float* ws = (float*)d_ws;

  float* feats = ws + OFF_FEATS;
  float* e_buf = ws + OFF_E;
  float* s_buf = ws + OFF_S;
  float* t1    = ws + OFF_T1;
  float* proto = ws + OFF_PROTO;

  k_prep<<<2793, 256, 0, stream>>>(conv_w[1], conv_w[2], conv_w[3], conv_w[4],
                                   trans_w, ws);
  k_main<<<250, 1024, 0, stream>>>(support, query,
                                   conv_w[0], bn_g[0], bn_b[0],
                                   bn_g[1], bn_b[1], bn_g[2], bn_b[2],
                                   bn_g[3], bn_b[3], bn_g[4], bn_b[4],
                                   trans_b, ws, feats, e_buf);
  k_routing<<<10, 256, 0, stream>>>(e_buf, proto);
  k_t1<<<800, 256, 0, stream>>>(proto, bil_w, t1);
  k_score<<<300, 256, 0, stream>>>(t1, feats + 100 * 256, score_w, s_buf);
  k_lsm<<<1, 256, 0, stream>>>(s_buf, score_b, out);
}